// Round 19
// baseline (296.233 us; speedup 1.0000x reference)
//
#include <hip/hip_runtime.h>

typedef __bf16 bf16;
typedef __bf16 bf16x8 __attribute__((ext_vector_type(8)));
typedef __bf16 bf16x4 __attribute__((ext_vector_type(4)));
typedef float  f32x4  __attribute__((ext_vector_type(4)));

__device__ __forceinline__ f32x4 mfma16(bf16x8 a, bf16x8 b, f32x4 c) {
  return __builtin_amdgcn_mfma_f32_16x16x32_bf16(a, b, c, 0, 0, 0);
}

__device__ __forceinline__ void gload16(const bf16* g, bf16* l) {
  __builtin_amdgcn_global_load_lds(
      (const __attribute__((address_space(1))) void*)g,
      (__attribute__((address_space(3))) void*)l, 16, 0, 0);
}

// ---------------------------------------------------------------------------
// Shared 64x64 transpose+cast body (in f32 [R][ldin] -> out bf16 [C][ldout])
// ---------------------------------------------------------------------------
__device__ __forceinline__ void tc64_body(const float* __restrict__ in,
                                          bf16* __restrict__ out,
                                          int ldin, int ldout, int bx, int by,
                                          bf16 (*t)[68]) {
  const int c0 = bx * 64, r0 = by * 64;
  const int g4 = threadIdx.x & 15;
  const int q  = threadIdx.x >> 4;
  #pragma unroll
  for (int i = 0; i < 4; ++i) {
    const int r = q + i * 16;
    const float4 v = *(const float4*)&in[(size_t)(r0 + r) * ldin + c0 + g4 * 4];
    bf16x4 b;
    b[0] = (bf16)v.x; b[1] = (bf16)v.y; b[2] = (bf16)v.z; b[3] = (bf16)v.w;
    *(bf16x4*)&t[r][g4 * 4] = b;
  }
  __syncthreads();
  #pragma unroll
  for (int i = 0; i < 4; ++i) {
    const int c = q + i * 16;
    bf16x4 b;
    b[0] = t[g4 * 4 + 0][c]; b[1] = t[g4 * 4 + 1][c];
    b[2] = t[g4 * 4 + 2][c]; b[3] = t[g4 * 4 + 3][c];
    *(bf16x4*)&out[(size_t)(c0 + c) * ldout + r0 + g4 * 4] = b;
  }
}

// ---------------------------------------------------------------------------
// prep1: cast_x || wqT || wkT || wvT  (fused; one launch)
// ---------------------------------------------------------------------------
__global__ void prep1(const float* __restrict__ x, bf16* __restrict__ xb,
                      const float* __restrict__ wq, const float* __restrict__ wk,
                      const float* __restrict__ wv, bf16* __restrict__ wT) {
  __shared__ bf16 t[64][68];
  const int b = blockIdx.x;
  if (b < 8192) {
    const int i = b * 256 + threadIdx.x;
    const float4 v = ((const float4*)x)[i];
    bf16x4 o;
    o[0] = (bf16)v.x; o[1] = (bf16)v.y; o[2] = (bf16)v.z; o[3] = (bf16)v.w;
    *(bf16x4*)&xb[(size_t)i * 4] = o;
  } else if (b < 12288) {
    const int bb = b - 8192;
    tc64_body(wq, wT, 4096, 4096, bb & 63, bb >> 6, t);
  } else if (b < 13312) {
    const int bb = b - 12288;
    tc64_body(wk, wT + (size_t)16777216, 1024, 4096, bb & 15, bb >> 4, t);
  } else {
    const int bb = b - 13312;
    tc64_body(wv, wT + (size_t)20971520, 1024, 4096, bb & 15, bb >> 4, t);
  }
}

// ---------------------------------------------------------------------------
// prep2: rope_q || rope_k || permute_v(+cache_v) || woT  (fused; one launch)
// ---------------------------------------------------------------------------
__global__ void prep2(bf16* __restrict__ qkv, bf16* __restrict__ kp,
                      float* __restrict__ ck, bf16* __restrict__ vp,
                      float* __restrict__ cv, const float* __restrict__ wo,
                      bf16* __restrict__ wT, const float* __restrict__ cs,
                      const float* __restrict__ sn) {
  __shared__ bf16 t[64][68];
  const int b = blockIdx.x;
  if (b < 16384) {                       // rope_q in place (cols 0..4095)
    const int idx = b * 256 + threadIdx.x;
    const int p  = idx & 63;
    const int sh = idx >> 6;
    const int h  = sh & 31;
    const int s  = sh >> 5;
    const float c  = cs[s * 64 + p];
    const float si = sn[s * 64 + p];
    const size_t ii = (size_t)s * 6144 + h * 128 + 2 * p;
    const float te = (float)qkv[ii], to = (float)qkv[ii + 1];
    qkv[ii]     = (bf16)(te * c - to * si);
    qkv[ii + 1] = (bf16)(te * si + to * c);
  } else if (b < 20480) {                // rope_k -> kp (frag-major) + cache_k
    const int idx = (b - 16384) * 256 + threadIdx.x;
    const int p  = idx & 63;
    const int sh = idx >> 6;
    const int h  = sh & 7;
    const int s  = sh >> 3;
    const float c  = cs[s * 64 + p];
    const float si = sn[s * 64 + p];
    const size_t ii = (size_t)s * 6144 + 4096 + h * 128 + 2 * p;
    const float te = (float)qkv[ii], to = (float)qkv[ii + 1];
    const float re = te * c - to * si;
    const float im = te * si + to * c;
    const size_t io = ((size_t)(h * 4 + (p >> 4)) * 2048 + s) * 32 + ((2 * p) & 31);
    kp[io]     = (bf16)re;
    kp[io + 1] = (bf16)im;
    const size_t ic = (size_t)s * 1024 + h * 128 + 2 * p;
    ck[ic]     = re;
    ck[ic + 1] = im;
  } else if (b < 22528) {                // permute_v + cache_v (cols 5120..6143)
    bf16 (*t32)[33] = (bf16(*)[33])&t[0][0];
    const int bb  = b - 20480;
    const int sb  = bb & 63;
    const int yy  = bb >> 6;
    const int kvh = yy >> 2;
    const int dt  = yy & 3;
    const int x = threadIdx.x & 31, y = threadIdx.x >> 5;
    #pragma unroll
    for (int i = 0; i < 32; i += 8) {
      const bf16 v = qkv[(size_t)(sb * 32 + y + i) * 6144 + 5120 +
                         kvh * 128 + dt * 32 + x];
      t32[y + i][x] = v;
      cv[(size_t)(sb * 32 + y + i) * 1024 + kvh * 128 + dt * 32 + x] = (float)v;
    }
    __syncthreads();
    #pragma unroll
    for (int i = 0; i < 32; i += 8)
      vp[((size_t)(kvh * 64 + sb) * 128 + dt * 32 + y + i) * 32 + x] = t32[x][y + i];
  } else {                               // woT
    const int bb = b - 22528;
    tc64_body(wo, wT, 4096, 4096, bb & 63, bb >> 6, t);
  }
}

#define MMQ(MB, NB)                                                            \
  _Pragma("unroll")                                                            \
  for (int mi = 0; mi < 4; ++mi)                                               \
    _Pragma("unroll")                                                          \
    for (int ni = 0; ni < 2; ++ni)                                             \
      _Pragma("unroll")                                                        \
      for (int kk = 0; kk < 2; ++kk)                                           \
        acc[MB + mi][NB + ni] =                                                \
            mfma16(ar[mi][kk], br[NB + ni][kk], acc[MB + mi][NB + ni]);

#define MM24(MB)                                                               \
  _Pragma("unroll")                                                            \
  for (int mi = 0; mi < 4; ++mi)                                               \
    _Pragma("unroll")                                                          \
    for (int ni = 0; ni < 3; ++ni)                                             \
      _Pragma("unroll")                                                        \
      for (int kk = 0; kk < 2; ++kk)                                           \
        acc[MB + mi][ni] = mfma16(ar[mi][kk], br[ni][kk], acc[MB + mi][ni]);

#define PH_OPEN                                                                \
  __builtin_amdgcn_s_barrier();                                                \
  asm volatile("s_waitcnt lgkmcnt(0)" ::: "memory");                           \
  __builtin_amdgcn_s_setprio(1);

#define PH_CLOSE                                                               \
  __builtin_amdgcn_s_setprio(0);                                               \
  __builtin_amdgcn_s_barrier();

// ---------------------------------------------------------------------------
// 8-phase 256x256 GEMM (m201 template), split-K=2 variant for out-proj.
// ---------------------------------------------------------------------------
template <typename OutT, int NSPLIT>
__global__ __launch_bounds__(512, 2)
void gemm8(const bf16* __restrict__ A, const bf16* __restrict__ Bt,
           OutT* __restrict__ C0, OutT* __restrict__ C1,
           int M, int N, int K, int ldc) {
  __shared__ __attribute__((aligned(16))) bf16 lds[65536];  // 128 KiB
  char* ldsc = (char*)lds;
  constexpr int AO0 = 0, BO0 = 32768, AO1 = 65536, BO1 = 98304;

  const int t    = threadIdx.x;
  const int w    = t >> 6;
  const int lane = t & 63;
  const int l15  = lane & 15;
  const int lg   = lane >> 4;
  const int wm   = w >> 2;
  const int wn   = w & 3;
  const int hb   = wn >> 1;

  const int nbm = M >> 8;
  const int nb2 = nbm * NSPLIT;
  const int cpx = (nb2 * (N >> 8)) >> 3;
  const int lid = ((int)blockIdx.x & 7) * cpx + ((int)blockIdx.x >> 3);
  const int bn  = (lid / nb2) * 256;
  const int rem = lid % nb2;
  const int kh  = rem / nbm;
  const int bm  = (rem % nbm) * 256;
  const int Kloc = K / NSPLIT;
  const int koff = kh * Kloc;
  OutT* __restrict__ C = (NSPLIT == 2 && kh) ? C1 : C0;

  const int d0     = t * 16;
  const int dsw    = d0 ^ (((d0 >> 9) & 1) << 5);
  const int srow_s = (dsw >> 6) & 127;
  const int scol_e = (dsw & 63) >> 1;

  auto stg = [&](const bf16* P, int rowbase, int tile, int half, int region) {
    const bf16* s = P + (size_t)(rowbase + half * 128 + srow_s) * K +
                    koff + tile * 64 + scol_e;
    gload16(s,      (bf16*)(ldsc + region + half * 16384 + w * 1024));
    gload16(s + 32, (bf16*)(ldsc + region + half * 16384 + 8192 + w * 1024));
  };
  auto lda = [&](int AO, int m, int kk) -> bf16x8 {
    int byte = AO + wm * 16384 + kk * 8192 + (m * 16 + l15) * 64 + lg * 16;
    byte ^= ((byte >> 9) & 1) << 5;
    return *(const bf16x8*)(ldsc + byte);
  };
  auto ldb = [&](int BO, int n, int kk) -> bf16x8 {
    int byte = BO + hb * 16384 + kk * 8192 +
               ((wn & 1) * 64 + n * 16 + l15) * 64 + lg * 16;
    byte ^= ((byte >> 9) & 1) << 5;
    return *(const bf16x8*)(ldsc + byte);
  };

  f32x4 acc[8][4] = {};
  bf16x8 ar[4][2], br[4][2];

  const int NT = Kloc >> 6;
  const int NI = Kloc >> 7;

  stg(A,  bm, 0, 0, AO0);  stg(A,  bm, 0, 1, AO0);
  stg(Bt, bn, 0, 0, BO0);  stg(Bt, bn, 0, 1, BO0);
  stg(Bt, bn, 1, 0, BO1);  stg(Bt, bn, 1, 1, BO1);
  asm volatile("s_waitcnt vmcnt(4)" ::: "memory");
  __builtin_amdgcn_s_barrier();

  #pragma unroll 1
  for (int it = 0; it < NI; ++it) {
    const int t1 = 2 * it + 1;
    const int t2 = (2 * it + 2 < NT) ? 2 * it + 2 : NT - 1;
    const int t3 = (2 * it + 3 < NT) ? 2 * it + 3 : NT - 1;

    #pragma unroll
    for (int mi = 0; mi < 4; ++mi) {
      ar[mi][0] = lda(AO0, mi, 0); ar[mi][1] = lda(AO0, mi, 1);
    }
    #pragma unroll
    for (int ni = 0; ni < 2; ++ni) {
      br[ni][0] = ldb(BO0, ni, 0); br[ni][1] = ldb(BO0, ni, 1);
    }
    stg(A, bm, t1, 0, AO1);
    PH_OPEN; MMQ(0, 0); PH_CLOSE;
    #pragma unroll
    for (int ni = 2; ni < 4; ++ni) {
      br[ni][0] = ldb(BO0, ni, 0); br[ni][1] = ldb(BO0, ni, 1);
    }
    stg(A, bm, t1, 1, AO1);
    PH_OPEN; MMQ(0, 2); PH_CLOSE;
    #pragma unroll
    for (int mi = 0; mi < 4; ++mi) {
      ar[mi][0] = lda(AO0, 4 + mi, 0); ar[mi][1] = lda(AO0, 4 + mi, 1);
    }
    stg(Bt, bn, t2, 0, BO0);
    PH_OPEN; MMQ(4, 0); PH_CLOSE;
    stg(Bt, bn, t2, 1, BO0);
    PH_OPEN; MMQ(4, 2);
    __builtin_amdgcn_s_setprio(0);
    asm volatile("s_waitcnt vmcnt(4)" ::: "memory");
    __builtin_amdgcn_s_barrier();
    #pragma unroll
    for (int mi = 0; mi < 4; ++mi) {
      ar[mi][0] = lda(AO1, mi, 0); ar[mi][1] = lda(AO1, mi, 1);
    }
    #pragma unroll
    for (int ni = 0; ni < 2; ++ni) {
      br[ni][0] = ldb(BO1, ni, 0); br[ni][1] = ldb(BO1, ni, 1);
    }
    stg(A, bm, t2, 0, AO0);
    PH_OPEN; MMQ(0, 0); PH_CLOSE;
    #pragma unroll
    for (int ni = 2; ni < 4; ++ni) {
      br[ni][0] = ldb(BO1, ni, 0); br[ni][1] = ldb(BO1, ni, 1);
    }
    stg(A, bm, t2, 1, AO0);
    PH_OPEN; MMQ(0, 2); PH_CLOSE;
    #pragma unroll
    for (int mi = 0; mi < 4; ++mi) {
      ar[mi][0] = lda(AO1, 4 + mi, 0); ar[mi][1] = lda(AO1, 4 + mi, 1);
    }
    stg(Bt, bn, t3, 0, BO1);
    PH_OPEN; MMQ(4, 0); PH_CLOSE;
    stg(Bt, bn, t3, 1, BO1);
    PH_OPEN; MMQ(4, 2);
    __builtin_amdgcn_s_setprio(0);
    asm volatile("s_waitcnt vmcnt(4)" ::: "memory");
    __builtin_amdgcn_s_barrier();
  }

  #pragma unroll
  for (int mi = 0; mi < 8; ++mi)
    #pragma unroll
    for (int ni = 0; ni < 4; ++ni)
      #pragma unroll
      for (int rr = 0; rr < 4; ++rr)
        C[(size_t)(bm + wm * 128 + mi * 16 + lg * 4 + rr) * ldc +
          (bn + wn * 64 + ni * 16 + l15)] = (OutT)acc[mi][ni][rr];
}

// ---------------------------------------------------------------------------
// 256x192 GEMM, merged 4-phase schedule (24 MFMA per phase, even duty cycle).
// Per iteration (2 K-tiles): P1 {read A m0-3 + B n0-2 (buf0); stage A(t1)->buf1},
// P2 {read A m4-7; stage B(t2)x3->buf0; gate vmcnt(3)}, P3/P4 mirrored on buf1.
// Ledger: issue order A(t1)4,B(t2)3,A(t2)4,B(t3)3; each gate leaves exactly the
// 3 newest B loads outstanding => vmcnt(3). WAR: every stage targets a region
// whose last ds_reads retired at the prior phase's lgkmcnt(0)+barrier.
// ---------------------------------------------------------------------------
__global__ __launch_bounds__(512, 2)
void gemm8n192(const bf16* __restrict__ A, const bf16* __restrict__ Bt,
               bf16* __restrict__ C, int M, int N, int K, int ldc) {
  __shared__ __attribute__((aligned(16))) bf16 lds[57344];  // 112 KiB
  char* ldsc = (char*)lds;
  constexpr int AO0 = 0, BO0 = 32768, AO1 = 57344, BO1 = 90112;

  const int t    = threadIdx.x;
  const int w    = t >> 6;
  const int lane = t & 63;
  const int l15  = lane & 15;
  const int lg   = lane >> 4;
  const int wm   = w >> 2;
  const int wn   = w & 3;

  const int cpx = 32;
  const int lid = ((int)blockIdx.x & 7) * cpx + ((int)blockIdx.x >> 3);
  const int bn  = (lid >> 3) * 192;
  const int bm  = (lid & 7) * 256;

  const int d0     = t * 16;
  const int dsw    = d0 ^ (((d0 >> 9) & 1) << 5);
  const int srow_a = (dsw >> 6) & 127;
  const int scol_e = (dsw & 63) >> 1;
  const int rw_b   = (t >> 2) & 63;
  const int kk_b   = t >> 8;

  auto stga = [&](int tile, int half, int region) {
    const bf16* s = A + (size_t)(bm + half * 128 + srow_a) * K + tile * 64 + scol_e;
    gload16(s,      (bf16*)(ldsc + region + half * 16384 + w * 1024));
    gload16(s + 32, (bf16*)(ldsc + region + half * 16384 + 8192 + w * 1024));
  };
  auto stgb = [&](int tile, int third, int region) {
    const bf16* s = Bt + (size_t)(bn + third * 64 + rw_b) * K +
                    tile * 64 + kk_b * 32 + scol_e;
    gload16(s, (bf16*)(ldsc + region + third * 8192 + w * 1024));
  };
  auto lda = [&](int AO, int m, int kk) -> bf16x8 {
    int byte = AO + wm * 16384 + kk * 8192 + (m * 16 + l15) * 64 + lg * 16;
    byte ^= ((byte >> 9) & 1) << 5;
    return *(const bf16x8*)(ldsc + byte);
  };
  auto ldb = [&](int BO, int n, int kk) -> bf16x8 {
    const int row = wn * 48 + n * 16 + l15;
    int byte = BO + (row >> 6) * 8192 + kk * 4096 + (row & 63) * 64 + lg * 16;
    byte ^= ((byte >> 9) & 1) << 5;
    return *(const bf16x8*)(ldsc + byte);
  };

  f32x4 acc[8][3] = {};
  bf16x8 ar[4][2], br[3][2];

  const int NT = K >> 6;
  const int NI = K >> 7;

  // prologue: tile0 (A halves + B thirds) -> buf0, tile1 B thirds -> buf1
  stga(0, 0, AO0); stga(0, 1, AO0);
  stgb(0, 0, BO0); stgb(0, 1, BO0); stgb(0, 2, BO0);
  stgb(1, 0, BO1); stgb(1, 1, BO1); stgb(1, 2, BO1);
  asm volatile("s_waitcnt vmcnt(3)" ::: "memory");
  __builtin_amdgcn_s_barrier();

  #pragma unroll 1
  for (int it = 0; it < NI; ++it) {
    const int t1 = 2 * it + 1;
    const int t2 = (2 * it + 2 < NT) ? 2 * it + 2 : NT - 1;
    const int t3 = (2 * it + 3 < NT) ? 2 * it + 3 : NT - 1;

    // P1: read A(buf0) m0-3 + B(buf0) n0-2 ; stage A(t1) h0+h1 -> buf1
    #pragma unroll
    for (int mi = 0; mi < 4; ++mi) {
      ar[mi][0] = lda(AO0, mi, 0); ar[mi][1] = lda(AO0, mi, 1);
    }
    #pragma unroll
    for (int ni = 0; ni < 3; ++ni) {
      br[ni][0] = ldb(BO0, ni, 0); br[ni][1] = ldb(BO0, ni, 1);
    }
    stga(t1, 0, AO1); stga(t1, 1, AO1);
    PH_OPEN; MM24(0); PH_CLOSE;
    // P2: read A(buf0) m4-7 ; stage B(t2) thirds -> buf0 ; gate vmcnt(3)
    #pragma unroll
    for (int mi = 0; mi < 4; ++mi) {
      ar[mi][0] = lda(AO0, 4 + mi, 0); ar[mi][1] = lda(AO0, 4 + mi, 1);
    }
    stgb(t2, 0, BO0); stgb(t2, 1, BO0); stgb(t2, 2, BO0);
    PH_OPEN; MM24(4);
    __builtin_amdgcn_s_setprio(0);
    asm volatile("s_waitcnt vmcnt(3)" ::: "memory");
    __builtin_amdgcn_s_barrier();
    // P3: read A(buf1) m0-3 + B(buf1) n0-2 ; stage A(t2) -> buf0
    #pragma unroll
    for (int mi = 0; mi < 4; ++mi) {
      ar[mi][0] = lda(AO1, mi, 0); ar[mi][1] = lda(AO1, mi, 1);
    }
    #pragma unroll
    for (int ni = 0; ni < 3; ++ni) {
      br[ni][0] = ldb(BO1, ni, 0); br[ni][1] = ldb(BO1, ni, 1);
    }
    stga(t2, 0, AO0); stga(t2, 1, AO0);
    PH_OPEN; MM24(0); PH_CLOSE;
    // P4: read A(buf1) m4-7 ; stage B(t3) thirds -> buf1 ; gate vmcnt(3)
    #pragma unroll
    for (int mi = 0; mi < 4; ++mi) {
      ar[mi][0] = lda(AO1, 4 + mi, 0); ar[mi][1] = lda(AO1, 4 + mi, 1);
    }
    stgb(t3, 0, BO1); stgb(t3, 1, BO1); stgb(t3, 2, BO1);
    PH_OPEN; MM24(4);
    __builtin_amdgcn_s_setprio(0);
    asm volatile("s_waitcnt vmcnt(3)" ::: "memory");
    __builtin_amdgcn_s_barrier();
  }

  #pragma unroll
  for (int mi = 0; mi < 8; ++mi)
    #pragma unroll
    for (int ni = 0; ni < 3; ++ni)
      #pragma unroll
      for (int rr = 0; rr < 4; ++rr)
        C[(size_t)(bm + wm * 128 + mi * 16 + lg * 4 + rr) * ldc +
          (bn + wn * 48 + ni * 16 + l15)] = (bf16)acc[mi][ni][rr];
}

// out[i] = (f32)p0[i] + (f32)p1[i], 4 elems/thread
__global__ void reduce_out(const bf16* __restrict__ p0, const bf16* __restrict__ p1,
                           float* __restrict__ out) {
  const int i = blockIdx.x * 256 + threadIdx.x;
  const bf16x4 a = *(const bf16x4*)&p0[(size_t)i * 4];
  const bf16x4 b = *(const bf16x4*)&p1[(size_t)i * 4];
  float4 o;
  o.x = (float)a[0] + (float)b[0];
  o.y = (float)a[1] + (float)b[1];
  o.z = (float)a[2] + (float)b[2];
  o.w = (float)a[3] + (float)b[3];
  *(float4*)&out[(size_t)i * 4] = o;
}

// ---------------------------------------------------------------------------
// Causal flash attention (round-12/15 proven structure, unchanged).
// ---------------------------------------------------------------------------
__global__ __launch_bounds__(256, 3)
void attn_fwd(const bf16* __restrict__ Q, const bf16* __restrict__ Kp,
              const bf16* __restrict__ Vp, bf16* __restrict__ O) {
  __shared__ __attribute__((aligned(16))) bf16 Kb[8192];
  __shared__ __attribute__((aligned(16))) bf16 Vb[8192];
  __shared__ __attribute__((aligned(16))) bf16 P_lds[4][16][72];
  const int id   = blockIdx.x;
  const int qt   = 31 - (id >> 5);
  const int kvh  = id & 7;
  const int sub  = (id >> 3) & 3;
  const int h    = kvh * 4 + sub;
  const int t    = threadIdx.x;
  const int w    = t >> 6;
  const int lane = t & 63;
  const int l15  = lane & 15;
  const int lg   = lane >> 4;
  const float scale = 0.08838834764831845f;
  const bf16* Kh = Kp + (size_t)kvh * 262144;
  const bf16* Vh = Vp + (size_t)kvh * 262144;
  const int koff = (t >> 2) * 32 + (t & 3) * 8;

  const int qw  = qt * 64 + w * 16;
  const int myq = qw + l15;

  bf16x8 qf[4];
  #pragma unroll
  for (int ds = 0; ds < 4; ++ds)
    qf[ds] = *(const bf16x8*)&Q[(size_t)myq * 6144 + h * 128 + ds * 32 + lg * 8];

  f32x4 o[8] = {};
  float m = -1e30f, ell = 0.f;

  #pragma unroll
  for (int i = 0; i < 4; ++i)
    gload16(Kh + (size_t)i * 65536 + koff, Kb + i * 2048 + w * 512);
  #pragma unroll
  for (int i = 0; i < 4; ++i)
    gload16(Vh + (size_t)i * 2048 + koff, Vb + i * 2048 + w * 512);
  __syncthreads();

  #pragma unroll 1
  for (int kt = 0; kt <= qt; ++kt) {
    f32x4 T[4] = {};
    __builtin_amdgcn_s_setprio(1);
    #pragma unroll
    for (int kb = 0; kb < 4; ++kb)
      #pragma unroll
      for (int ds = 0; ds < 4; ++ds) {
        bf16x8 kf = *(const bf16x8*)&Kb[(ds * 64 + kb * 16 + l15) * 32 + lg * 8];
        T[kb] = mfma16(kf, qf[ds], T[kb]);
      }
    __builtin_amdgcn_s_setprio(0);
    __syncthreads();
    if (kt < qt) {
      #pragma unroll
      for (int i = 0; i < 4; ++i)
        gload16(Kh + (size_t)i * 65536 + (kt + 1) * 2048 + koff,
                Kb + i * 2048 + w * 512);
    }

    float pv[16];
    float pmax = -1e30f;
    if (kt == qt) {
      #pragma unroll
      for (int kb = 0; kb < 4; ++kb)
        #pragma unroll
        for (int r = 0; r < 4; ++r) {
          const int key = qt * 64 + kb * 16 + lg * 4 + r;
          const float s = (key > myq) ? -1e30f : T[kb][r] * scale;
          pv[kb * 4 + r] = s;
          pmax = fmaxf(pmax, s);
        }
    } else {
      #pragma unroll
      for (int kb = 0; kb < 4; ++kb)
        #pragma unroll
        for (int r = 0; r < 4; ++r) {
          const float s = T[kb][r] * scale;
          pv[kb * 4 + r] = s;
          pmax = fmaxf(pmax, s);
        }
    }
    float base = m;
    if (!__all(pmax - m <= 8.f)) {
      float wmax = pmax;
      wmax = fmaxf(wmax, __shfl_xor(wmax, 16));
      wmax = fmaxf(wmax, __shfl_xor(wmax, 32));
      const float newm = fmaxf(m, wmax);
      const float corr = __expf(m - newm);
      ell *= corr;
      m = newm; base = newm;
      float sf[4];
      #pragma unroll
      for (int r = 0; r < 4; ++r) sf[r] = __shfl(corr, lg * 4 + r);
      #pragma unroll
      for (int df = 0; df < 8; ++df)
        #pragma unroll
        for (int r = 0; r < 4; ++r) o[df][r] *= sf[r];
    }
    bf16 pb[16];
    float tsum = 0.f;
    #pragma unroll
    for (int i = 0; i < 16; ++i) {
      const float p = __expf(pv[i] - base);
      tsum += p;
      pb[i] = (bf16)p;
    }
    ell += tsum;

    #pragma unroll
    for (int kb = 0; kb < 4; ++kb) {
      bf16x4 pk;
      pk[0] = pb[kb * 4 + 0]; pk[1] = pb[kb * 4 + 1];
      pk[2] = pb[kb * 4 + 2]; pk[3] = pb[kb * 4 + 3];
      *(bf16x4*)&P_lds[w][l15][kb * 16 + lg * 4] = pk;
    }
    __builtin_amdgcn_s_setprio(1);
    #pragma unroll
    for (int ks = 0; ks < 2; ++ks) {
      bf16x8 pa = *(const bf16x8*)&P_lds[w][l15][ks * 32 + lg * 8];
      #pragma unroll
      for (int df = 0; df < 8; ++df) {
        bf16x8 vf = *(const bf16x8*)&Vb[(ks * 128 + df * 16 + l15) * 32 + lg * 8];
        o[df] = mfma16(pa, vf, o[df]);
      }
    }
    __builtin_amdgcn_s_setprio(0);
    __syncthreads();
    if (kt < qt) {
      #pragma unroll
      for (int i = 0; i < 4; ++i)
        gload16(Vh + (size_t)(kt + 1) * 8192 + i * 2048 + koff,
                Vb + i * 2048 + w * 512);
    }
  }

  ell += __shfl_xor(ell, 16);
  ell += __shfl_xor(ell, 32);
  float er[4];
  #pragma unroll
  for (int r = 0; r < 4; ++r) er[r] = 1.f / __shfl(ell, lg * 4 + r);
  #pragma unroll
  for (int df = 0; df < 8; ++df)
    #pragma unroll
    for (int r = 0; r < 4; ++r)
      O[(size_t)(qw + lg * 4 + r) * 4096 + h * 128 + df * 16 + l15] =
          (bf16)(o[df][r] * er[r]);
}

// ---------------------------------------------------------------------------
extern "C" void kernel_launch(void* const* d_in, const int* in_sizes, int n_in,
                              void* d_out, int out_size, void* d_ws, size_t ws_size,
                              hipStream_t stream) {
  const float* x    = (const float*)d_in[0];
  const float* wq   = (const float*)d_in[1];
  const float* wk   = (const float*)d_in[2];
  const float* wv   = (const float*)d_in[3];
  const float* wo   = (const float*)d_in[4];
  const float* cosf_ = (const float*)d_in[5];
  const float* sinf_ = (const float*)d_in[6];

  float* out     = (float*)d_out;               // [2048][4096]
  float* cache_k = out + (size_t)8388608;
  float* cache_v = cache_k + (size_t)2097152;
  bf16* qkv = (bf16*)d_out;                     // [2048][6144] scratch overlay

  bf16* ws = (bf16*)d_ws;
  bf16* wT = ws;                                // wqT|wkT|wvT, later woT
  bf16* kp = ws + (size_t)25165824;
  bf16* vp = kp + (size_t)2097152;
  bf16* xb = vp + (size_t)2097152;
  bf16* aout = xb;
  bf16* part1 = wT + (size_t)16777216;
  bf16* part0 = ws + (size_t)37748736;

  prep1<<<14336, 256, 0, stream>>>(x, xb, wq, wk, wv, wT);
  gemm8n192<<<256, 512, 0, stream>>>(xb, wT, qkv, 2048, 6144, 4096, 6144);
  prep2<<<26624, 256, 0, stream>>>(qkv, kp, cache_k, vp, cache_v, wo, wT,
                                   cosf_, sinf_);
  attn_fwd<<<1024, 256, 0, stream>>>(qkv, kp, vp, aout);
  gemm8<bf16, 2><<<256, 512, 0, stream>>>(aout, wT, part0, part1,
                                          2048, 4096, 4096, 4096);
  reduce_out<<<8192, 256, 0, stream>>>(part0, part1, out);
}

// Round 20
// 290.072 us; speedup vs baseline: 1.0212x; 1.0212x over previous
//
#include <hip/hip_runtime.h>

typedef __bf16 bf16;
typedef __bf16 bf16x8 __attribute__((ext_vector_type(8)));
typedef __bf16 bf16x4 __attribute__((ext_vector_type(4)));
typedef float  f32x4  __attribute__((ext_vector_type(4)));

__device__ __forceinline__ f32x4 mfma16(bf16x8 a, bf16x8 b, f32x4 c) {
  return __builtin_amdgcn_mfma_f32_16x16x32_bf16(a, b, c, 0, 0, 0);
}

__device__ __forceinline__ void gload16(const bf16* g, bf16* l) {
  __builtin_amdgcn_global_load_lds(
      (const __attribute__((address_space(1))) void*)g,
      (__attribute__((address_space(3))) void*)l, 16, 0, 0);
}

// ---------------------------------------------------------------------------
// Shared 64x64 transpose+cast body (in f32 [R][ldin] -> out bf16 [C][ldout])
// ---------------------------------------------------------------------------
__device__ __forceinline__ void tc64_body(const float* __restrict__ in,
                                          bf16* __restrict__ out,
                                          int ldin, int ldout, int bx, int by,
                                          bf16 (*t)[68]) {
  const int c0 = bx * 64, r0 = by * 64;
  const int g4 = threadIdx.x & 15;
  const int q  = threadIdx.x >> 4;
  #pragma unroll
  for (int i = 0; i < 4; ++i) {
    const int r = q + i * 16;
    const float4 v = *(const float4*)&in[(size_t)(r0 + r) * ldin + c0 + g4 * 4];
    bf16x4 b;
    b[0] = (bf16)v.x; b[1] = (bf16)v.y; b[2] = (bf16)v.z; b[3] = (bf16)v.w;
    *(bf16x4*)&t[r][g4 * 4] = b;
  }
  __syncthreads();
  #pragma unroll
  for (int i = 0; i < 4; ++i) {
    const int c = q + i * 16;
    bf16x4 b;
    b[0] = t[g4 * 4 + 0][c]; b[1] = t[g4 * 4 + 1][c];
    b[2] = t[g4 * 4 + 2][c]; b[3] = t[g4 * 4 + 3][c];
    *(bf16x4*)&out[(size_t)(c0 + c) * ldout + r0 + g4 * 4] = b;
  }
}

// ---------------------------------------------------------------------------
// prep1: cast_x || wqT || wkT || wvT  (fused; one launch)
// ---------------------------------------------------------------------------
__global__ void prep1(const float* __restrict__ x, bf16* __restrict__ xb,
                      const float* __restrict__ wq, const float* __restrict__ wk,
                      const float* __restrict__ wv, bf16* __restrict__ wT) {
  __shared__ bf16 t[64][68];
  const int b = blockIdx.x;
  if (b < 8192) {
    const int i = b * 256 + threadIdx.x;
    const float4 v = ((const float4*)x)[i];
    bf16x4 o;
    o[0] = (bf16)v.x; o[1] = (bf16)v.y; o[2] = (bf16)v.z; o[3] = (bf16)v.w;
    *(bf16x4*)&xb[(size_t)i * 4] = o;
  } else if (b < 12288) {
    const int bb = b - 8192;
    tc64_body(wq, wT, 4096, 4096, bb & 63, bb >> 6, t);
  } else if (b < 13312) {
    const int bb = b - 12288;
    tc64_body(wk, wT + (size_t)16777216, 1024, 4096, bb & 15, bb >> 4, t);
  } else {
    const int bb = b - 13312;
    tc64_body(wv, wT + (size_t)20971520, 1024, 4096, bb & 15, bb >> 4, t);
  }
}

// ---------------------------------------------------------------------------
// prep2: rope_q || rope_k || permute_v(+cache_v) || woT  (fused; one launch)
// ---------------------------------------------------------------------------
__global__ void prep2(bf16* __restrict__ qkv, bf16* __restrict__ kp,
                      float* __restrict__ ck, bf16* __restrict__ vp,
                      float* __restrict__ cv, const float* __restrict__ wo,
                      bf16* __restrict__ wT, const float* __restrict__ cs,
                      const float* __restrict__ sn) {
  __shared__ bf16 t[64][68];
  const int b = blockIdx.x;
  if (b < 16384) {                       // rope_q in place (cols 0..4095)
    const int idx = b * 256 + threadIdx.x;
    const int p  = idx & 63;
    const int sh = idx >> 6;
    const int h  = sh & 31;
    const int s  = sh >> 5;
    const float c  = cs[s * 64 + p];
    const float si = sn[s * 64 + p];
    const size_t ii = (size_t)s * 6144 + h * 128 + 2 * p;
    const float te = (float)qkv[ii], to = (float)qkv[ii + 1];
    qkv[ii]     = (bf16)(te * c - to * si);
    qkv[ii + 1] = (bf16)(te * si + to * c);
  } else if (b < 20480) {                // rope_k -> kp (frag-major) + cache_k
    const int idx = (b - 16384) * 256 + threadIdx.x;
    const int p  = idx & 63;
    const int sh = idx >> 6;
    const int h  = sh & 7;
    const int s  = sh >> 3;
    const float c  = cs[s * 64 + p];
    const float si = sn[s * 64 + p];
    const size_t ii = (size_t)s * 6144 + 4096 + h * 128 + 2 * p;
    const float te = (float)qkv[ii], to = (float)qkv[ii + 1];
    const float re = te * c - to * si;
    const float im = te * si + to * c;
    const size_t io = ((size_t)(h * 4 + (p >> 4)) * 2048 + s) * 32 + ((2 * p) & 31);
    kp[io]     = (bf16)re;
    kp[io + 1] = (bf16)im;
    const size_t ic = (size_t)s * 1024 + h * 128 + 2 * p;
    ck[ic]     = re;
    ck[ic + 1] = im;
  } else if (b < 22528) {                // permute_v + cache_v (cols 5120..6143)
    bf16 (*t32)[33] = (bf16(*)[33])&t[0][0];
    const int bb  = b - 20480;
    const int sb  = bb & 63;
    const int yy  = bb >> 6;
    const int kvh = yy >> 2;
    const int dt  = yy & 3;
    const int x = threadIdx.x & 31, y = threadIdx.x >> 5;
    #pragma unroll
    for (int i = 0; i < 32; i += 8) {
      const bf16 v = qkv[(size_t)(sb * 32 + y + i) * 6144 + 5120 +
                         kvh * 128 + dt * 32 + x];
      t32[y + i][x] = v;
      cv[(size_t)(sb * 32 + y + i) * 1024 + kvh * 128 + dt * 32 + x] = (float)v;
    }
    __syncthreads();
    #pragma unroll
    for (int i = 0; i < 32; i += 8)
      vp[((size_t)(kvh * 64 + sb) * 128 + dt * 32 + y + i) * 32 + x] = t32[x][y + i];
  } else {                               // woT
    const int bb = b - 22528;
    tc64_body(wo, wT, 4096, 4096, bb & 63, bb >> 6, t);
  }
}

#define MMQ(MB, NB)                                                            \
  _Pragma("unroll")                                                            \
  for (int mi = 0; mi < 4; ++mi)                                               \
    _Pragma("unroll")                                                          \
    for (int ni = 0; ni < 2; ++ni)                                             \
      _Pragma("unroll")                                                        \
      for (int kk = 0; kk < 2; ++kk)                                           \
        acc[MB + mi][NB + ni] =                                                \
            mfma16(ar[mi][kk], br[NB + ni][kk], acc[MB + mi][NB + ni]);

#define MMQ1(MB)                                                               \
  _Pragma("unroll")                                                            \
  for (int mi = 0; mi < 4; ++mi)                                               \
    _Pragma("unroll")                                                          \
    for (int kk = 0; kk < 2; ++kk)                                             \
      acc[MB + mi][2] = mfma16(ar[mi][kk], br[2][kk], acc[MB + mi][2]);

#define PH_OPEN                                                                \
  __builtin_amdgcn_s_barrier();                                                \
  asm volatile("s_waitcnt lgkmcnt(0)" ::: "memory");                           \
  __builtin_amdgcn_s_setprio(1);

#define PH_CLOSE                                                               \
  __builtin_amdgcn_s_setprio(0);                                               \
  __builtin_amdgcn_s_barrier();

// ---------------------------------------------------------------------------
// 8-phase 256x192 GEMM (round-18 proven version): 256 blocks = 100% fill.
// ---------------------------------------------------------------------------
__global__ __launch_bounds__(512, 2)
void gemm8n192(const bf16* __restrict__ A, const bf16* __restrict__ Bt,
               bf16* __restrict__ C, int M, int N, int K, int ldc) {
  __shared__ __attribute__((aligned(16))) bf16 lds[57344];  // 112 KiB
  char* ldsc = (char*)lds;
  constexpr int AO0 = 0, BO0 = 32768, AO1 = 57344, BO1 = 90112;

  const int t    = threadIdx.x;
  const int w    = t >> 6;
  const int lane = t & 63;
  const int l15  = lane & 15;
  const int lg   = lane >> 4;
  const int wm   = w >> 2;
  const int wn   = w & 3;

  const int cpx = 32;
  const int lid = ((int)blockIdx.x & 7) * cpx + ((int)blockIdx.x >> 3);
  const int bn  = (lid >> 3) * 192;
  const int bm  = (lid & 7) * 256;

  const int d0     = t * 16;
  const int dsw    = d0 ^ (((d0 >> 9) & 1) << 5);
  const int srow_a = (dsw >> 6) & 127;
  const int scol_e = (dsw & 63) >> 1;
  const int rw_b   = (t >> 2) & 63;
  const int kk_b   = t >> 8;

  auto stga = [&](int tile, int half, int region) {
    const bf16* s = A + (size_t)(bm + half * 128 + srow_a) * K + tile * 64 + scol_e;
    gload16(s,      (bf16*)(ldsc + region + half * 16384 + w * 1024));
    gload16(s + 32, (bf16*)(ldsc + region + half * 16384 + 8192 + w * 1024));
  };
  auto stgb = [&](int tile, int third, int region) {
    const bf16* s = Bt + (size_t)(bn + third * 64 + rw_b) * K +
                    tile * 64 + kk_b * 32 + scol_e;
    gload16(s, (bf16*)(ldsc + region + third * 8192 + w * 1024));
  };
  auto lda = [&](int AO, int m, int kk) -> bf16x8 {
    int byte = AO + wm * 16384 + kk * 8192 + (m * 16 + l15) * 64 + lg * 16;
    byte ^= ((byte >> 9) & 1) << 5;
    return *(const bf16x8*)(ldsc + byte);
  };
  auto ldb = [&](int BO, int n, int kk) -> bf16x8 {
    const int row = wn * 48 + n * 16 + l15;
    int byte = BO + (row >> 6) * 8192 + kk * 4096 + (row & 63) * 64 + lg * 16;
    byte ^= ((byte >> 9) & 1) << 5;
    return *(const bf16x8*)(ldsc + byte);
  };

  f32x4 acc[8][3] = {};
  bf16x8 ar[4][2], br[3][2];

  const int NT = K >> 6;
  const int NI = K >> 7;

  stga(0, 0, AO0); stga(0, 1, AO0);
  stgb(0, 0, BO0); stgb(0, 1, BO0); stgb(0, 2, BO0);
  stgb(1, 0, BO1); stgb(1, 1, BO1); stgb(1, 2, BO1);
  asm volatile("s_waitcnt vmcnt(3)" ::: "memory");
  __builtin_amdgcn_s_barrier();

  #pragma unroll 1
  for (int it = 0; it < NI; ++it) {
    const int t1 = 2 * it + 1;
    const int t2 = (2 * it + 2 < NT) ? 2 * it + 2 : NT - 1;
    const int t3 = (2 * it + 3 < NT) ? 2 * it + 3 : NT - 1;

    #pragma unroll
    for (int mi = 0; mi < 4; ++mi) {
      ar[mi][0] = lda(AO0, mi, 0); ar[mi][1] = lda(AO0, mi, 1);
    }
    #pragma unroll
    for (int ni = 0; ni < 2; ++ni) {
      br[ni][0] = ldb(BO0, ni, 0); br[ni][1] = ldb(BO0, ni, 1);
    }
    stga(t1, 0, AO1);
    PH_OPEN; MMQ(0, 0); PH_CLOSE;
    br[2][0] = ldb(BO0, 2, 0); br[2][1] = ldb(BO0, 2, 1);
    stga(t1, 1, AO1);
    PH_OPEN; MMQ1(0); PH_CLOSE;
    #pragma unroll
    for (int mi = 0; mi < 4; ++mi) {
      ar[mi][0] = lda(AO0, 4 + mi, 0); ar[mi][1] = lda(AO0, 4 + mi, 1);
    }
    stgb(t2, 0, BO0); stgb(t2, 1, BO0);
    PH_OPEN; MMQ(4, 0); PH_CLOSE;
    stgb(t2, 2, BO0);
    PH_OPEN; MMQ1(4);
    __builtin_amdgcn_s_setprio(0);
    asm volatile("s_waitcnt vmcnt(3)" ::: "memory");
    __builtin_amdgcn_s_barrier();
    #pragma unroll
    for (int mi = 0; mi < 4; ++mi) {
      ar[mi][0] = lda(AO1, mi, 0); ar[mi][1] = lda(AO1, mi, 1);
    }
    #pragma unroll
    for (int ni = 0; ni < 2; ++ni) {
      br[ni][0] = ldb(BO1, ni, 0); br[ni][1] = ldb(BO1, ni, 1);
    }
    stga(t2, 0, AO0);
    PH_OPEN; MMQ(0, 0); PH_CLOSE;
    br[2][0] = ldb(BO1, 2, 0); br[2][1] = ldb(BO1, 2, 1);
    stga(t2, 1, AO0);
    PH_OPEN; MMQ1(0); PH_CLOSE;
    #pragma unroll
    for (int mi = 0; mi < 4; ++mi) {
      ar[mi][0] = lda(AO1, 4 + mi, 0); ar[mi][1] = lda(AO1, 4 + mi, 1);
    }
    stgb(t3, 0, BO1); stgb(t3, 1, BO1);
    PH_OPEN; MMQ(4, 0); PH_CLOSE;
    stgb(t3, 2, BO1);
    PH_OPEN; MMQ1(4);
    __builtin_amdgcn_s_setprio(0);
    asm volatile("s_waitcnt vmcnt(3)" ::: "memory");
    __builtin_amdgcn_s_barrier();
  }

  #pragma unroll
  for (int mi = 0; mi < 8; ++mi)
    #pragma unroll
    for (int ni = 0; ni < 3; ++ni)
      #pragma unroll
      for (int rr = 0; rr < 4; ++rr)
        C[(size_t)(bm + wm * 128 + mi * 16 + lg * 4 + rr) * ldc +
          (bn + wn * 48 + ni * 16 + l15)] = (bf16)acc[mi][ni][rr];
}

// ---------------------------------------------------------------------------
// 256x128 GEMM, f32 epilogue (out-proj): 8m x 32n = 256 blocks = 100% fill,
// no split-K partials, no reduce pass. Same swizzle frame as gemm8 (bit9^bit5,
// region bases multiple of 1024 with bit9=0). B tile = 128 rows = one 16KB
// stage (2 gloads, [kk-page 8KB][row][32elem]). 4 phases/iter x 16 MFMA.
// Ledger: prologue 8 issued, drain 6 -> vmcnt(2); per-gate outstanding 8,
// drain 6 (oldest = prev B 2 + new A 4) -> vmcnt(2), leaving 2 newest B.
// WAR: each stage targets a region whose last ds_reads retired at the
// preceding PH_OPEN lgkmcnt(0) + barrier.
// ---------------------------------------------------------------------------
__global__ __launch_bounds__(512, 2)
void gemm8n128(const bf16* __restrict__ A, const bf16* __restrict__ Bt,
               float* __restrict__ C, int M, int N, int K, int ldc) {
  __shared__ __attribute__((aligned(16))) bf16 lds[49152];  // 96 KiB
  char* ldsc = (char*)lds;
  constexpr int AO0 = 0, AO1 = 32768, BO0 = 65536, BO1 = 81920;

  const int t    = threadIdx.x;
  const int w    = t >> 6;
  const int lane = t & 63;
  const int l15  = lane & 15;
  const int lg   = lane >> 4;
  const int wm   = w >> 2;
  const int wn   = w & 3;

  const int cpx = 32;                                   // 256 blocks / 8 XCDs
  const int lid = ((int)blockIdx.x & 7) * cpx + ((int)blockIdx.x >> 3);
  const int bn  = (lid >> 3) * 128;                     // 32 n-panels
  const int bm  = (lid & 7) * 256;                      // 8 m-panels

  const int d0     = t * 16;
  const int dsw    = d0 ^ (((d0 >> 9) & 1) << 5);
  const int srow_s = (dsw >> 6) & 127;
  const int scol_e = (dsw & 63) >> 1;

  auto stga = [&](int tile, int half, int region) {
    const bf16* s = A + (size_t)(bm + half * 128 + srow_s) * K + tile * 64 + scol_e;
    gload16(s,      (bf16*)(ldsc + region + half * 16384 + w * 1024));
    gload16(s + 32, (bf16*)(ldsc + region + half * 16384 + 8192 + w * 1024));
  };
  auto stgb = [&](int tile, int region) {
    const bf16* s = Bt + (size_t)(bn + srow_s) * K + tile * 64 + scol_e;
    gload16(s,      (bf16*)(ldsc + region + w * 1024));
    gload16(s + 32, (bf16*)(ldsc + region + 8192 + w * 1024));
  };
  auto lda = [&](int AO, int m, int kk) -> bf16x8 {
    int byte = AO + wm * 16384 + kk * 8192 + (m * 16 + l15) * 64 + lg * 16;
    byte ^= ((byte >> 9) & 1) << 5;
    return *(const bf16x8*)(ldsc + byte);
  };
  auto ldb = [&](int BO, int n, int kk) -> bf16x8 {
    const int row = wn * 32 + n * 16 + l15;             // 0..127
    int byte = BO + kk * 8192 + row * 64 + lg * 16;
    byte ^= ((byte >> 9) & 1) << 5;
    return *(const bf16x8*)(ldsc + byte);
  };

  f32x4 acc[8][2] = {};
  bf16x8 ar[4][2], br[2][2];

  const int NT = K >> 6;
  const int NI = K >> 7;

  // prologue: tile0 A+B -> buf0; tile1 B -> buf1
  stga(0, 0, AO0); stga(0, 1, AO0);
  stgb(0, BO0);
  stgb(1, BO1);
  asm volatile("s_waitcnt vmcnt(2)" ::: "memory");
  __builtin_amdgcn_s_barrier();

  #pragma unroll 1
  for (int it = 0; it < NI; ++it) {
    const int t1 = 2 * it + 1;
    const int t2 = (2 * it + 2 < NT) ? 2 * it + 2 : NT - 1;
    const int t3 = (2 * it + 3 < NT) ? 2 * it + 3 : NT - 1;

    // P1: read A(buf0) m0-3 + B(buf0); stage A(t1) h0 -> buf1
    #pragma unroll
    for (int mi = 0; mi < 4; ++mi) {
      ar[mi][0] = lda(AO0, mi, 0); ar[mi][1] = lda(AO0, mi, 1);
    }
    #pragma unroll
    for (int ni = 0; ni < 2; ++ni) {
      br[ni][0] = ldb(BO0, ni, 0); br[ni][1] = ldb(BO0, ni, 1);
    }
    stga(t1, 0, AO1);
    PH_OPEN; MMQ(0, 0); PH_CLOSE;
    // P2: read A(buf0) m4-7; stage A(t1) h1 -> buf1 + B(t2) -> buf0; gate
    #pragma unroll
    for (int mi = 0; mi < 4; ++mi) {
      ar[mi][0] = lda(AO0, 4 + mi, 0); ar[mi][1] = lda(AO0, 4 + mi, 1);
    }
    stga(t1, 1, AO1);
    stgb(t2, BO0);
    PH_OPEN; MMQ(4, 0);
    __builtin_amdgcn_s_setprio(0);
    asm volatile("s_waitcnt vmcnt(2)" ::: "memory");
    __builtin_amdgcn_s_barrier();
    // P3: read A(buf1) m0-3 + B(buf1); stage A(t2) h0 -> buf0
    #pragma unroll
    for (int mi = 0; mi < 4; ++mi) {
      ar[mi][0] = lda(AO1, mi, 0); ar[mi][1] = lda(AO1, mi, 1);
    }
    #pragma unroll
    for (int ni = 0; ni < 2; ++ni) {
      br[ni][0] = ldb(BO1, ni, 0); br[ni][1] = ldb(BO1, ni, 1);
    }
    stga(t2, 0, AO0);
    PH_OPEN; MMQ(0, 0); PH_CLOSE;
    // P4: read A(buf1) m4-7; stage A(t2) h1 -> buf0 + B(t3) -> buf1; gate
    #pragma unroll
    for (int mi = 0; mi < 4; ++mi) {
      ar[mi][0] = lda(AO1, 4 + mi, 0); ar[mi][1] = lda(AO1, 4 + mi, 1);
    }
    stga(t2, 1, AO0);
    stgb(t3, BO1);
    PH_OPEN; MMQ(4, 0);
    __builtin_amdgcn_s_setprio(0);
    asm volatile("s_waitcnt vmcnt(2)" ::: "memory");
    __builtin_amdgcn_s_barrier();
  }

  #pragma unroll
  for (int mi = 0; mi < 8; ++mi)
    #pragma unroll
    for (int ni = 0; ni < 2; ++ni)
      #pragma unroll
      for (int rr = 0; rr < 4; ++rr)
        C[(size_t)(bm + wm * 128 + mi * 16 + lg * 4 + rr) * ldc +
          (bn + wn * 32 + ni * 16 + l15)] = acc[mi][ni][rr];
}

// ---------------------------------------------------------------------------
// Causal flash attention (round-12/15 proven structure, unchanged).
// ---------------------------------------------------------------------------
__global__ __launch_bounds__(256, 3)
void attn_fwd(const bf16* __restrict__ Q, const bf16* __restrict__ Kp,
              const bf16* __restrict__ Vp, bf16* __restrict__ O) {
  __shared__ __attribute__((aligned(16))) bf16 Kb[8192];
  __shared__ __attribute__((aligned(16))) bf16 Vb[8192];
  __shared__ __attribute__((aligned(16))) bf16 P_lds[4][16][72];
  const int id   = blockIdx.x;
  const int qt   = 31 - (id >> 5);
  const int kvh  = id & 7;
  const int sub  = (id >> 3) & 3;
  const int h    = kvh * 4 + sub;
  const int t    = threadIdx.x;
  const int w    = t >> 6;
  const int lane = t & 63;
  const int l15  = lane & 15;
  const int lg   = lane >> 4;
  const float scale = 0.08838834764831845f;
  const bf16* Kh = Kp + (size_t)kvh * 262144;
  const bf16* Vh = Vp + (size_t)kvh * 262144;
  const int koff = (t >> 2) * 32 + (t & 3) * 8;

  const int qw  = qt * 64 + w * 16;
  const int myq = qw + l15;

  bf16x8 qf[4];
  #pragma unroll
  for (int ds = 0; ds < 4; ++ds)
    qf[ds] = *(const bf16x8*)&Q[(size_t)myq * 6144 + h * 128 + ds * 32 + lg * 8];

  f32x4 o[8] = {};
  float m = -1e30f, ell = 0.f;

  #pragma unroll
  for (int i = 0; i < 4; ++i)
    gload16(Kh + (size_t)i * 65536 + koff, Kb + i * 2048 + w * 512);
  #pragma unroll
  for (int i = 0; i < 4; ++i)
    gload16(Vh + (size_t)i * 2048 + koff, Vb + i * 2048 + w * 512);
  __syncthreads();

  #pragma unroll 1
  for (int kt = 0; kt <= qt; ++kt) {
    f32x4 T[4] = {};
    __builtin_amdgcn_s_setprio(1);
    #pragma unroll
    for (int kb = 0; kb < 4; ++kb)
      #pragma unroll
      for (int ds = 0; ds < 4; ++ds) {
        bf16x8 kf = *(const bf16x8*)&Kb[(ds * 64 + kb * 16 + l15) * 32 + lg * 8];
        T[kb] = mfma16(kf, qf[ds], T[kb]);
      }
    __builtin_amdgcn_s_setprio(0);
    __syncthreads();
    if (kt < qt) {
      #pragma unroll
      for (int i = 0; i < 4; ++i)
        gload16(Kh + (size_t)i * 65536 + (kt + 1) * 2048 + koff,
                Kb + i * 2048 + w * 512);
    }

    float pv[16];
    float pmax = -1e30f;
    if (kt == qt) {
      #pragma unroll
      for (int kb = 0; kb < 4; ++kb)
        #pragma unroll
        for (int r = 0; r < 4; ++r) {
          const int key = qt * 64 + kb * 16 + lg * 4 + r;
          const float s = (key > myq) ? -1e30f : T[kb][r] * scale;
          pv[kb * 4 + r] = s;
          pmax = fmaxf(pmax, s);
        }
    } else {
      #pragma unroll
      for (int kb = 0; kb < 4; ++kb)
        #pragma unroll
        for (int r = 0; r < 4; ++r) {
          const float s = T[kb][r] * scale;
          pv[kb * 4 + r] = s;
          pmax = fmaxf(pmax, s);
        }
    }
    float base = m;
    if (!__all(pmax - m <= 8.f)) {
      float wmax = pmax;
      wmax = fmaxf(wmax, __shfl_xor(wmax, 16));
      wmax = fmaxf(wmax, __shfl_xor(wmax, 32));
      const float newm = fmaxf(m, wmax);
      const float corr = __expf(m - newm);
      ell *= corr;
      m = newm; base = newm;
      float sf[4];
      #pragma unroll
      for (int r = 0; r < 4; ++r) sf[r] = __shfl(corr, lg * 4 + r);
      #pragma unroll
      for (int df = 0; df < 8; ++df)
        #pragma unroll
        for (int r = 0; r < 4; ++r) o[df][r] *= sf[r];
    }
    bf16 pb[16];
    float tsum = 0.f;
    #pragma unroll
    for (int i = 0; i < 16; ++i) {
      const float p = __expf(pv[i] - base);
      tsum += p;
      pb[i] = (bf16)p;
    }
    ell += tsum;

    #pragma unroll
    for (int kb = 0; kb < 4; ++kb) {
      bf16x4 pk;
      pk[0] = pb[kb * 4 + 0]; pk[1] = pb[kb * 4 + 1];
      pk[2] = pb[kb * 4 + 2]; pk[3] = pb[kb * 4 + 3];
      *(bf16x4*)&P_lds[w][l15][kb * 16 + lg * 4] = pk;
    }
    __builtin_amdgcn_s_setprio(1);
    #pragma unroll
    for (int ks = 0; ks < 2; ++ks) {
      bf16x8 pa = *(const bf16x8*)&P_lds[w][l15][ks * 32 + lg * 8];
      #pragma unroll
      for (int df = 0; df < 8; ++df) {
        bf16x8 vf = *(const bf16x8*)&Vb[(ks * 128 + df * 16 + l15) * 32 + lg * 8];
        o[df] = mfma16(pa, vf, o[df]);
      }
    }
    __builtin_amdgcn_s_setprio(0);
    __syncthreads();
    if (kt < qt) {
      #pragma unroll
      for (int i = 0; i < 4; ++i)
        gload16(Vh + (size_t)(kt + 1) * 8192 + i * 2048 + koff,
                Vb + i * 2048 + w * 512);
    }
  }

  ell += __shfl_xor(ell, 16);
  ell += __shfl_xor(ell, 32);
  float er[4];
  #pragma unroll
  for (int r = 0; r < 4; ++r) er[r] = 1.f / __shfl(ell, lg * 4 + r);
  #pragma unroll
  for (int df = 0; df < 8; ++df)
    #pragma unroll
    for (int r = 0; r < 4; ++r)
      O[(size_t)(qw + lg * 4 + r) * 4096 + h * 128 + df * 16 + l15] =
          (bf16)(o[df][r] * er[r]);
}

// ---------------------------------------------------------------------------
extern "C" void kernel_launch(void* const* d_in, const int* in_sizes, int n_in,
                              void* d_out, int out_size, void* d_ws, size_t ws_size,
                              hipStream_t stream) {
  const float* x    = (const float*)d_in[0];
  const float* wq   = (const float*)d_in[1];
  const float* wk   = (const float*)d_in[2];
  const float* wv   = (const float*)d_in[3];
  const float* wo   = (const float*)d_in[4];
  const float* cosf_ = (const float*)d_in[5];
  const float* sinf_ = (const float*)d_in[6];

  float* out     = (float*)d_out;               // [2048][4096]
  float* cache_k = out + (size_t)8388608;
  float* cache_v = cache_k + (size_t)2097152;
  bf16* qkv = (bf16*)d_out;                     // [2048][6144] scratch overlay
                                                // (dead before out-proj writes)

  bf16* ws = (bf16*)d_ws;
  bf16* wT = ws;                                // wqT|wkT|wvT, later woT
  bf16* kp = ws + (size_t)25165824;
  bf16* vp = kp + (size_t)2097152;
  bf16* xb = vp + (size_t)2097152;
  bf16* aout = xb;                              // attn output reuses xb

  prep1<<<14336, 256, 0, stream>>>(x, xb, wq, wk, wv, wT);
  gemm8n192<<<256, 512, 0, stream>>>(xb, wT, qkv, 2048, 6144, 4096, 6144);
  prep2<<<26624, 256, 0, stream>>>(qkv, kp, cache_k, vp, cache_v, wo, wT,
                                   cosf_, sinf_);
  attn_fwd<<<1024, 256, 0, stream>>>(qkv, kp, vp, aout);
  // out-proj: 256x128 tiles, 256 blocks full fill, direct f32 epilogue
  gemm8n128<<<256, 512, 0, stream>>>(aout, wT, out, 2048, 4096, 4096, 4096);
}